// Round 8
// baseline (277.113 us; speedup 1.0000x reference)
//
#include <hip/hip_runtime.h>
#include <hip/hip_bf16.h>
#include <hip/hip_cooperative_groups.h>

namespace cg = cooperative_groups;

// ---------- types ----------
typedef __attribute__((ext_vector_type(8))) short short8;   // 8 x bf16 (4 VGPRs)
typedef __attribute__((ext_vector_type(4))) float f32x4;    // 16x16 MFMA accumulator

typedef unsigned short u16;

__device__ __forceinline__ u16 f32_to_bf16(float f) {
    unsigned int u = __float_as_uint(f);
    u += 0x7fffu + ((u >> 16) & 1u);   // round-to-nearest-even
    return (u16)(u >> 16);
}
__device__ __forceinline__ float bf16_to_f32(u16 h) {
    return __uint_as_float(((unsigned int)h) << 16);
}

// async global->LDS, 16B per lane; LDS dest = wave-uniform base + lane*16
__device__ __forceinline__ void gload16(const u16* g, u16* lds_base) {
    __builtin_amdgcn_global_load_lds(
        (const __attribute__((address_space(1))) void*)g,
        (__attribute__((address_space(3))) void*)lds_base, 16, 0, 0);
}

// ======== GEMM cores: C = A[M,K] * Bt[N,K]^T, both row-major, contiguous K ====
// global_load_lds width=16 staging, XOR chunk swizzle (row r, slot p holds
// global chunk p^(r&7)). 16x16x32 MFMA fragment reads = one 16B chunk.
// This read pattern measured 0 SQ_LDS_BANK_CONFLICT (R3/R5/R7); the 32x32
// variant measured 6.29M (R4) — don't switch shapes without re-measuring.

struct Frag128 { f32x4 acc[4][4]; int lane, wm, wn; };

__device__ __forceinline__ void gemm_core_128(
    const u16* __restrict__ A, const u16* __restrict__ Bt, int K, int lda, int ldb,
    int row0, int col0, u16* sA, u16* sB, Frag128& fr)
{
    const int t    = threadIdx.x;
    const int lane = t & 63;
    const int wave = t >> 6;
    fr.lane = lane;
    fr.wm = (wave >> 1) * 64;
    fr.wn = (wave & 1) * 64;
    const int lr = lane & 15;

#pragma unroll
    for (int i = 0; i < 4; ++i)
#pragma unroll
        for (int j = 0; j < 4; ++j)
            fr.acc[i][j] = (f32x4){0.f, 0.f, 0.f, 0.f};

    const int srow = lane >> 3;
    const int gc   = (lane & 7) ^ srow;
    for (int k0 = 0; k0 < K; k0 += 64) {
        __syncthreads();
#pragma unroll
        for (int c = 0; c < 4; ++c) {
            const int rb = c * 32 + wave * 8;
            const int r  = rb + srow;
            gload16(A  + (long long)(row0 + r) * lda + k0 + gc * 8, &sA[rb * 64]);
            gload16(Bt + (long long)(col0 + r) * ldb + k0 + gc * 8, &sB[rb * 64]);
        }
        __syncthreads();

#pragma unroll
        for (int kk = 0; kk < 64; kk += 32) {
            const int cb = (lane >> 4) + (kk >> 3);
            const int sl = (cb ^ (lr & 7)) * 8;
            short8 af[4], bf[4];
#pragma unroll
            for (int i = 0; i < 4; ++i) {
                af[i] = *(const short8*)(&sA[(fr.wm + i * 16 + lr) * 64 + sl]);
                bf[i] = *(const short8*)(&sB[(fr.wn + i * 16 + lr) * 64 + sl]);
            }
#pragma unroll
            for (int i = 0; i < 4; ++i)
#pragma unroll
                for (int j = 0; j < 4; ++j)
                    fr.acc[i][j] = __builtin_amdgcn_mfma_f32_16x16x32_bf16(
                        af[i], bf[j], fr.acc[i][j], 0, 0, 0);
        }
    }
}

struct FragN64 { f32x4 acc[2][4]; int lane, wm; };

__device__ __forceinline__ void gemm_core_n64(
    const u16* __restrict__ A, const u16* __restrict__ Bt, int K, int lda, int ldb,
    int row0, int col0, u16* sA, u16* sB, FragN64& fr)
{
    const int t    = threadIdx.x;
    const int lane = t & 63;
    const int wave = t >> 6;
    fr.lane = lane;
    fr.wm = wave * 32;
    const int lr = lane & 15;

#pragma unroll
    for (int i = 0; i < 2; ++i)
#pragma unroll
        for (int j = 0; j < 4; ++j)
            fr.acc[i][j] = (f32x4){0.f, 0.f, 0.f, 0.f};

    const int srow = lane >> 3;
    const int gc   = (lane & 7) ^ srow;
    for (int k0 = 0; k0 < K; k0 += 64) {
        __syncthreads();
#pragma unroll
        for (int c = 0; c < 4; ++c) {
            const int rb = c * 32 + wave * 8;
            gload16(A + (long long)(row0 + rb + srow) * lda + k0 + gc * 8,
                    &sA[rb * 64]);
        }
#pragma unroll
        for (int c = 0; c < 2; ++c) {
            const int rb = c * 32 + wave * 8;
            gload16(Bt + (long long)(col0 + rb + srow) * ldb + k0 + gc * 8,
                    &sB[rb * 64]);
        }
        __syncthreads();

#pragma unroll
        for (int kk = 0; kk < 64; kk += 32) {
            const int cb = (lane >> 4) + (kk >> 3);
            const int sl = (cb ^ (lr & 7)) * 8;
            short8 af[2], bf[4];
#pragma unroll
            for (int i = 0; i < 2; ++i)
                af[i] = *(const short8*)(&sA[(fr.wm + i * 16 + lr) * 64 + sl]);
#pragma unroll
            for (int j = 0; j < 4; ++j)
                bf[j] = *(const short8*)(&sB[(j * 16 + lr) * 64 + sl]);
#pragma unroll
            for (int i = 0; i < 2; ++i)
#pragma unroll
                for (int j = 0; j < 4; ++j)
                    fr.acc[i][j] = __builtin_amdgcn_mfma_f32_16x16x32_bf16(
                        af[i], bf[j], fr.acc[i][j], 0, 0, 0);
        }
    }
}

// C/D layout (16x16): col = lane&15, row = (lane>>4)*4 + reg   [m89/m91-verified]

// =====================================================================
// Mega-kernel: all phases in one cooperative launch (grid 1024 x 256).
// Eliminates ~70 us of inter-dispatch launch gaps measured across R5-R7.
// =====================================================================
__global__ __launch_bounds__(256, 4) void attn_mega(
    const float* __restrict__ x, const float* __restrict__ W,
    float* __restrict__ out,
    u16* __restrict__ Xb, u16* __restrict__ Wb, u16* __restrict__ QK,
    u16* __restrict__ VT, u16* __restrict__ P, u16* __restrict__ S)
{
    __shared__ __align__(16) u16 smem[2 * 128 * 64];   // 32 KB
    u16* sA = smem;
    u16* sB = smem + 128 * 64;

    const int bid = blockIdx.x;
    const int t   = threadIdx.x;
    cg::grid_group grid = cg::this_grid();

    // ---- phase 0: cast x then W to bf16. 2883584 float4 = 1024*256*11 exact.
    {
        const int NX4 = 8192 * 1024 / 4;
        int base = bid * 256 + t;
#pragma unroll
        for (int it = 0; it < 11; ++it) {
            int i = base + it * 262144;
            const float4* src; ushort4* dst; int idx;
            if (i < NX4) { src = (const float4*)x; dst = (ushort4*)Xb; idx = i; }
            else { src = (const float4*)W; dst = (ushort4*)Wb; idx = i - NX4; }
            float4 v = src[idx];
            ushort4 o;
            o.x = f32_to_bf16(v.x); o.y = f32_to_bf16(v.y);
            o.z = f32_to_bf16(v.z); o.w = f32_to_bf16(v.w);
            dst[idx] = o;
        }
    }
    grid.sync();

    // ---- phase 1a: QK projection. 1024 tiles of 128x128 over [8192,2048].
    {
        const int row0 = (bid >> 4) * 128, col0 = (bid & 15) * 128;
        Frag128 fr;
        gemm_core_128(Xb, Wb, 1024, 1024, 1024, row0, col0, sA, sB, fr);
        const int cr = (fr.lane >> 4) * 4, cc = fr.lane & 15;
#pragma unroll
        for (int i = 0; i < 4; ++i)
#pragma unroll
            for (int j = 0; j < 4; ++j)
#pragma unroll
                for (int r = 0; r < 4; ++r) {
                    int grow = row0 + fr.wm + i * 16 + cr + r;
                    int gcol = col0 + fr.wn + j * 16 + cc;
                    QK[(long long)grow * 2048 + gcol] = f32_to_bf16(fr.acc[i][j][r]);
                }
    }

    // ---- phase 1b: V projection stored transposed. 1024 tiles of 128x64.
    {
        const int row0 = (bid >> 4) * 128, col0 = (bid & 15) * 64;
        FragN64 fr;
        gemm_core_n64(Xb, Wb + 2048 * 1024, 1024, 1024, 1024, row0, col0, sA, sB, fr);
        const int cr = (fr.lane >> 4) * 4, cc = fr.lane & 15;
#pragma unroll
        for (int i = 0; i < 2; ++i) {
            int grow = row0 + fr.wm + i * 16 + cr;   // s base, 4-aligned
            int b = grow >> 11, s = grow & 2047;
#pragma unroll
            for (int j = 0; j < 4; ++j) {
                int d = col0 + j * 16 + cc;
                ushort4 o;
                o.x = f32_to_bf16(fr.acc[i][j][0]);
                o.y = f32_to_bf16(fr.acc[i][j][1]);
                o.z = f32_to_bf16(fr.acc[i][j][2]);
                o.w = f32_to_bf16(fr.acc[i][j][3]);
                *(ushort4*)(&VT[((long long)(b * 1024 + d)) * 2048 + s]) = o;
            }
        }
    }
    grid.sync();

    // ---- phase 2: S = Q K^T (bf16). 1024 tiles: 16x x 16y x 4z.
    {
        const int xx = bid & 15, yy = (bid >> 4) & 15, zz = bid >> 8;
        const long long boff = (long long)zz * 2048 * 2048;
        const u16* Q  = QK + boff;
        const u16* Kp = QK + boff + 1024;
        u16* Sb = S + boff;
        const int row0 = yy * 128, col0 = xx * 128;
        Frag128 fr;
        gemm_core_128(Q, Kp, 1024, 2048, 2048, row0, col0, sA, sB, fr);
        const int cr = (fr.lane >> 4) * 4, cc = fr.lane & 15;
#pragma unroll
        for (int i = 0; i < 4; ++i)
#pragma unroll
            for (int j = 0; j < 4; ++j)
#pragma unroll
                for (int r = 0; r < 4; ++r) {
                    int grow = row0 + fr.wm + i * 16 + cr + r;
                    int gcol = col0 + fr.wn + j * 16 + cc;
                    Sb[(long long)grow * 2048 + gcol] = f32_to_bf16(fr.acc[i][j][r]);
                }
    }
    grid.sync();

    // ---- phase 3: softmax, 8 rows per block ----
    {
        float* red = (float*)smem;   // [8] reduction scratch
        const int lane = t & 63, w = t >> 6;
#pragma unroll 1
        for (int r8 = 0; r8 < 8; ++r8) {
            const long long row = (long long)bid * 8 + r8;
            const u16* s = S + row * 2048;
            u16* p = P + row * 2048;
            short8 raw = *(const short8*)(s + t * 8);
            float v[8];
            float m = -1e30f;
#pragma unroll
            for (int i = 0; i < 8; ++i) {
                v[i] = bf16_to_f32((u16)raw[i]) * 0.03125f;
                m = fmaxf(m, v[i]);
            }
#pragma unroll
            for (int off = 32; off > 0; off >>= 1) m = fmaxf(m, __shfl_xor(m, off, 64));
            __syncthreads();
            if (lane == 0) red[w] = m;
            __syncthreads();
            m = fmaxf(fmaxf(red[0], red[1]), fmaxf(red[2], red[3]));
            float sum = 0.f;
#pragma unroll
            for (int i = 0; i < 8; ++i) {
                v[i] = __expf(v[i] - m);
                sum += v[i];
            }
#pragma unroll
            for (int off = 32; off > 0; off >>= 1) sum += __shfl_xor(sum, off, 64);
            __syncthreads();
            if (lane == 0) red[4 + w] = sum;
            __syncthreads();
            const float inv = 1.0f / (red[4] + red[5] + red[6] + red[7]);
            short8 o;
#pragma unroll
            for (int i = 0; i < 8; ++i) o[i] = (short)f32_to_bf16(v[i] * inv);
            *(short8*)(p + t * 8) = o;
        }
    }
    grid.sync();

    // ---- phase 4: Y = P * VT^T (fp32). 1024 tiles of 128x64: 16x x 16y x 4z.
    {
        const int xx = bid & 15, yy = (bid >> 4) & 15, zz = bid >> 8;
        const u16* Pb  = P  + (long long)zz * 2048 * 2048;
        const u16* VTb = VT + (long long)zz * 1024 * 2048;
        float* Yb = out + (long long)zz * 2048 * 1024;
        const int row0 = yy * 128, col0 = xx * 64;
        FragN64 fr;
        gemm_core_n64(Pb, VTb, 2048, 2048, 2048, row0, col0, sA, sB, fr);
        const int cr = (fr.lane >> 4) * 4, cc = fr.lane & 15;
#pragma unroll
        for (int i = 0; i < 2; ++i)
#pragma unroll
            for (int j = 0; j < 4; ++j)
#pragma unroll
                for (int r = 0; r < 4; ++r) {
                    int grow = row0 + fr.wm + i * 16 + cr + r;
                    int gcol = col0 + j * 16 + cc;
                    Yb[(long long)grow * 1024 + gcol] = fr.acc[i][j][r];
                }
    }
}

// ====================== fallback (R7) kernels ======================
__global__ void cast_inputs(const float* __restrict__ x, u16* __restrict__ Xb,
                            const float* __restrict__ W, u16* __restrict__ Wb,
                            int nx4, int nw4) {
    int i = blockIdx.x * blockDim.x + threadIdx.x;
    const float* in; u16* out; int idx;
    if (i < nx4) { in = x; out = Xb; idx = i; }
    else { idx = i - nx4; if (idx >= nw4) return; in = W; out = Wb; }
    float4 v = ((const float4*)in)[idx];
    ushort4 o;
    o.x = f32_to_bf16(v.x); o.y = f32_to_bf16(v.y);
    o.z = f32_to_bf16(v.z); o.w = f32_to_bf16(v.w);
    ((ushort4*)out)[idx] = o;
}

__global__ __launch_bounds__(256) void gemm_qk(
    const u16* __restrict__ Xb, const u16* __restrict__ Wb, u16* __restrict__ QK)
{
    __shared__ u16 sA[128 * 64];
    __shared__ u16 sB[128 * 64];
    const int row0 = blockIdx.y * 128;
    const int col0 = blockIdx.x * 128;
    Frag128 fr;
    gemm_core_128(Xb, Wb, 1024, 1024, 1024, row0, col0, sA, sB, fr);
    const int cr = (fr.lane >> 4) * 4, cc = fr.lane & 15;
#pragma unroll
    for (int i = 0; i < 4; ++i)
#pragma unroll
        for (int j = 0; j < 4; ++j)
#pragma unroll
            for (int r = 0; r < 4; ++r) {
                int grow = row0 + fr.wm + i * 16 + cr + r;
                int gcol = col0 + fr.wn + j * 16 + cc;
                QK[(long long)grow * 2048 + gcol] = f32_to_bf16(fr.acc[i][j][r]);
            }
}

__global__ __launch_bounds__(256) void gemm_v(
    const u16* __restrict__ Xb, const u16* __restrict__ Wv, u16* __restrict__ VT)
{
    __shared__ u16 sA[128 * 64];
    __shared__ u16 sB[64 * 64];
    const int row0 = blockIdx.y * 128;
    const int col0 = blockIdx.x * 64;
    FragN64 fr;
    gemm_core_n64(Xb, Wv, 1024, 1024, 1024, row0, col0, sA, sB, fr);
    const int cr = (fr.lane >> 4) * 4, cc = fr.lane & 15;
#pragma unroll
    for (int i = 0; i < 2; ++i) {
        int grow = row0 + fr.wm + i * 16 + cr;
        int b = grow >> 11, s = grow & 2047;
#pragma unroll
        for (int j = 0; j < 4; ++j) {
            int d = col0 + j * 16 + cc;
            ushort4 o;
            o.x = f32_to_bf16(fr.acc[i][j][0]);
            o.y = f32_to_bf16(fr.acc[i][j][1]);
            o.z = f32_to_bf16(fr.acc[i][j][2]);
            o.w = f32_to_bf16(fr.acc[i][j][3]);
            *(ushort4*)(&VT[((long long)(b * 1024 + d)) * 2048 + s]) = o;
        }
    }
}

__global__ __launch_bounds__(256) void gemm_s(
    const u16* __restrict__ QK, u16* __restrict__ S)
{
    __shared__ u16 sA[128 * 64];
    __shared__ u16 sB[128 * 64];
    const long long boff = (long long)blockIdx.z * 2048 * 2048;
    const u16* Q  = QK + boff;
    const u16* Kp = QK + boff + 1024;
    u16* Sb = S + boff;
    const int row0 = blockIdx.y * 128;
    const int col0 = blockIdx.x * 128;
    Frag128 fr;
    gemm_core_128(Q, Kp, 1024, 2048, 2048, row0, col0, sA, sB, fr);
    const int cr = (fr.lane >> 4) * 4, cc = fr.lane & 15;
#pragma unroll
    for (int i = 0; i < 4; ++i)
#pragma unroll
        for (int j = 0; j < 4; ++j)
#pragma unroll
            for (int r = 0; r < 4; ++r) {
                int grow = row0 + fr.wm + i * 16 + cr + r;
                int gcol = col0 + fr.wn + j * 16 + cc;
                Sb[(long long)grow * 2048 + gcol] = f32_to_bf16(fr.acc[i][j][r]);
            }
}

__global__ __launch_bounds__(256) void gemm_pv(
    const u16* __restrict__ P, const u16* __restrict__ VT, float* __restrict__ Y)
{
    __shared__ u16 sA[128 * 64];
    __shared__ u16 sB[64 * 64];
    const u16* Pb  = P  + (long long)blockIdx.z * 2048 * 2048;
    const u16* VTb = VT + (long long)blockIdx.z * 1024 * 2048;
    float* Yb = Y + (long long)blockIdx.z * 2048 * 1024;
    const int row0 = blockIdx.y * 128;
    const int col0 = blockIdx.x * 64;
    FragN64 fr;
    gemm_core_n64(Pb, VTb, 2048, 2048, 2048, row0, col0, sA, sB, fr);
    const int cr = (fr.lane >> 4) * 4, cc = fr.lane & 15;
#pragma unroll
    for (int i = 0; i < 2; ++i)
#pragma unroll
        for (int j = 0; j < 4; ++j)
#pragma unroll
            for (int r = 0; r < 4; ++r) {
                int grow = row0 + fr.wm + i * 16 + cr + r;
                int gcol = col0 + j * 16 + cc;
                Yb[(long long)grow * 1024 + gcol] = fr.acc[i][j][r];
            }
}

__global__ __launch_bounds__(256) void softmax_rows(
    const u16* __restrict__ S, u16* __restrict__ P, float scale)
{
    const long long row = blockIdx.x;
    const u16* s = S + row * 2048;
    u16* p = P + row * 2048;
    const int t = threadIdx.x;
    const int lane = t & 63, w = t >> 6;
    short8 raw = *(const short8*)(s + t * 8);
    float v[8];
    float m = -1e30f;
#pragma unroll
    for (int i = 0; i < 8; ++i) {
        v[i] = bf16_to_f32((u16)raw[i]) * scale;
        m = fmaxf(m, v[i]);
    }
#pragma unroll
    for (int off = 32; off > 0; off >>= 1) m = fmaxf(m, __shfl_xor(m, off, 64));
    __shared__ float sm[4], ss[4];
    if (lane == 0) sm[w] = m;
    __syncthreads();
    m = fmaxf(fmaxf(sm[0], sm[1]), fmaxf(sm[2], sm[3]));
    float sum = 0.f;
#pragma unroll
    for (int i = 0; i < 8; ++i) {
        v[i] = __expf(v[i] - m);
        sum += v[i];
    }
#pragma unroll
    for (int off = 32; off > 0; off >>= 1) sum += __shfl_xor(sum, off, 64);
    if (lane == 0) ss[w] = sum;
    __syncthreads();
    const float inv = 1.0f / (ss[0] + ss[1] + ss[2] + ss[3]);
    short8 o;
#pragma unroll
    for (int i = 0; i < 8; ++i) o[i] = (short)f32_to_bf16(v[i] * inv);
    *(short8*)(p + t * 8) = o;
}

// ---------- launch ----------
extern "C" void kernel_launch(void* const* d_in, const int* in_sizes, int n_in,
                              void* d_out, int out_size, void* d_ws, size_t ws_size,
                              hipStream_t stream) {
    const float* x = (const float*)d_in[0];   // [4,2048,1024]
    const float* W = (const float*)d_in[1];   // [3072,1024]
    float* out = (float*)d_out;               // [4,2048,1024]

    char* ws = (char*)d_ws;
    // layout (bytes): Xb 16.8M | Wb 6.3M | QK 33.6M | VT 16.8M | P 33.6M | S 33.6M
    u16* Xb = (u16*)(ws);
    u16* Wb = (u16*)(ws + 16777216LL);
    u16* QK = (u16*)(ws + 23068672LL);
    u16* VT = (u16*)(ws + 56623104LL);
    u16* P  = (u16*)(ws + 73400320LL);
    u16* S  = (u16*)(ws + 106954752LL);

    // Cooperative mega-kernel needs 1024 co-resident blocks (4/CU on 256 CUs).
    // Deterministic occupancy query each call (no static guards).
    int maxb = 0;
    hipError_t oe = hipOccupancyMaxActiveBlocksPerMultiprocessor(
        &maxb, attn_mega, 256, 0);
    const bool coop = (oe == hipSuccess && maxb >= 4);

    if (coop) {
        void* args[] = {(void*)&x, (void*)&W, (void*)&out,
                        (void*)&Xb, (void*)&Wb, (void*)&QK,
                        (void*)&VT, (void*)&P, (void*)&S};
        hipLaunchCooperativeKernel(attn_mega, dim3(1024), dim3(256), args, 0,
                                   stream);
    } else {
        cast_inputs<<<11264, 256, 0, stream>>>(x, Xb, W, Wb,
                                               8192 * 1024 / 4, 3072 * 1024 / 4);
        gemm_qk<<<dim3(16, 64, 1), 256, 0, stream>>>(Xb, Wb, QK);
        gemm_v<<<dim3(16, 64, 1), 256, 0, stream>>>(Xb, Wb + 2048 * 1024, VT);
        gemm_s<<<dim3(16, 16, 4), 256, 0, stream>>>(QK, S);
        softmax_rows<<<8192, 256, 0, stream>>>(S, P, 0.03125f);
        gemm_pv<<<dim3(16, 16, 4), 256, 0, stream>>>(P, VT, out);
    }
}

// Round 9
// 263.853 us; speedup vs baseline: 1.0503x; 1.0503x over previous
//
#include <hip/hip_runtime.h>
#include <hip/hip_bf16.h>

// ---------- types ----------
typedef __attribute__((ext_vector_type(8))) short short8;   // 8 x bf16 (4 VGPRs)
typedef __attribute__((ext_vector_type(4))) float f32x4;    // 16x16 MFMA accumulator

typedef unsigned short u16;

__device__ __forceinline__ u16 f32_to_bf16(float f) {
    unsigned int u = __float_as_uint(f);
    u += 0x7fffu + ((u >> 16) & 1u);   // round-to-nearest-even
    return (u16)(u >> 16);
}
__device__ __forceinline__ float bf16_to_f32(u16 h) {
    return __uint_as_float(((unsigned int)h) << 16);
}

// async global->LDS, 16B per lane; LDS dest = wave-uniform base + lane*16
__device__ __forceinline__ void gload16(const u16* g, u16* lds_base) {
    __builtin_amdgcn_global_load_lds(
        (const __attribute__((address_space(1))) void*)g,
        (__attribute__((address_space(3))) void*)lds_base, 16, 0, 0);
}

// ---------- fused input cast: x then W, fp32 -> bf16, 4 elems/thread ----------
__global__ void cast_inputs(const float* __restrict__ x, u16* __restrict__ Xb,
                            const float* __restrict__ W, u16* __restrict__ Wb,
                            int nx4, int nw4) {
    int i = blockIdx.x * blockDim.x + threadIdx.x;
    const float* in; u16* out; int idx;
    if (i < nx4) { in = x; out = Xb; idx = i; }
    else { idx = i - nx4; if (idx >= nw4) return; in = W; out = Wb; }
    float4 v = ((const float4*)in)[idx];
    ushort4 o;
    o.x = f32_to_bf16(v.x); o.y = f32_to_bf16(v.y);
    o.z = f32_to_bf16(v.z); o.w = f32_to_bf16(v.w);
    ((ushort4*)out)[idx] = o;
}

// ======== GEMM cores: C = A[M,K] * Bt[N,K]^T, both row-major, contiguous K ====
// global_load_lds width=16 staging, XOR chunk swizzle (row r, slot p holds
// global chunk p^(r&7)). 16x16x32 MFMA fragment reads = one 16B chunk.
// This read pattern measured 0 SQ_LDS_BANK_CONFLICT (R3/R5/R7); the 32x32
// variant measured 6.29M (R4) — don't switch shapes without re-measuring.
// Per-block fact (R8 analysis): one 128x128xK=1024 tile block = ~43 us
// regardless of grid size (0.78 TF/block at 4 blocks/CU); grids < ~1024
// blocks leave CUs idle.

struct Frag128 { f32x4 acc[4][4]; int lane, wm, wn; };

__device__ __forceinline__ void gemm_core_128(
    const u16* __restrict__ A, const u16* __restrict__ Bt, int K, int lda, int ldb,
    int row0, int col0, u16* sA, u16* sB, Frag128& fr)
{
    const int t    = threadIdx.x;
    const int lane = t & 63;
    const int wave = t >> 6;
    fr.lane = lane;
    fr.wm = (wave >> 1) * 64;
    fr.wn = (wave & 1) * 64;
    const int lr = lane & 15;

#pragma unroll
    for (int i = 0; i < 4; ++i)
#pragma unroll
        for (int j = 0; j < 4; ++j)
            fr.acc[i][j] = (f32x4){0.f, 0.f, 0.f, 0.f};

    const int srow = lane >> 3;
    const int gc   = (lane & 7) ^ srow;
    for (int k0 = 0; k0 < K; k0 += 64) {
        __syncthreads();
#pragma unroll
        for (int c = 0; c < 4; ++c) {
            const int rb = c * 32 + wave * 8;
            const int r  = rb + srow;
            gload16(A  + (long long)(row0 + r) * lda + k0 + gc * 8, &sA[rb * 64]);
            gload16(Bt + (long long)(col0 + r) * ldb + k0 + gc * 8, &sB[rb * 64]);
        }
        __syncthreads();

#pragma unroll
        for (int kk = 0; kk < 64; kk += 32) {
            const int cb = (lane >> 4) + (kk >> 3);
            const int sl = (cb ^ (lr & 7)) * 8;
            short8 af[4], bf[4];
#pragma unroll
            for (int i = 0; i < 4; ++i) {
                af[i] = *(const short8*)(&sA[(fr.wm + i * 16 + lr) * 64 + sl]);
                bf[i] = *(const short8*)(&sB[(fr.wn + i * 16 + lr) * 64 + sl]);
            }
#pragma unroll
            for (int i = 0; i < 4; ++i)
#pragma unroll
                for (int j = 0; j < 4; ++j)
                    fr.acc[i][j] = __builtin_amdgcn_mfma_f32_16x16x32_bf16(
                        af[i], bf[j], fr.acc[i][j], 0, 0, 0);
        }
    }
}

struct FragN64 { f32x4 acc[2][4]; int lane, wm; };

__device__ __forceinline__ void gemm_core_n64(
    const u16* __restrict__ A, const u16* __restrict__ Bt, int K, int lda, int ldb,
    int row0, int col0, u16* sA, u16* sB, FragN64& fr)
{
    const int t    = threadIdx.x;
    const int lane = t & 63;
    const int wave = t >> 6;
    fr.lane = lane;
    fr.wm = wave * 32;
    const int lr = lane & 15;

#pragma unroll
    for (int i = 0; i < 2; ++i)
#pragma unroll
        for (int j = 0; j < 4; ++j)
            fr.acc[i][j] = (f32x4){0.f, 0.f, 0.f, 0.f};

    const int srow = lane >> 3;
    const int gc   = (lane & 7) ^ srow;
    for (int k0 = 0; k0 < K; k0 += 64) {
        __syncthreads();
#pragma unroll
        for (int c = 0; c < 4; ++c) {
            const int rb = c * 32 + wave * 8;
            gload16(A + (long long)(row0 + rb + srow) * lda + k0 + gc * 8,
                    &sA[rb * 64]);
        }
#pragma unroll
        for (int c = 0; c < 2; ++c) {
            const int rb = c * 32 + wave * 8;
            gload16(Bt + (long long)(col0 + rb + srow) * ldb + k0 + gc * 8,
                    &sB[rb * 64]);
        }
        __syncthreads();

#pragma unroll
        for (int kk = 0; kk < 64; kk += 32) {
            const int cb = (lane >> 4) + (kk >> 3);
            const int sl = (cb ^ (lr & 7)) * 8;
            short8 af[2], bf[4];
#pragma unroll
            for (int i = 0; i < 2; ++i)
                af[i] = *(const short8*)(&sA[(fr.wm + i * 16 + lr) * 64 + sl]);
#pragma unroll
            for (int j = 0; j < 4; ++j)
                bf[j] = *(const short8*)(&sB[(j * 16 + lr) * 64 + sl]);
#pragma unroll
            for (int i = 0; i < 2; ++i)
#pragma unroll
                for (int j = 0; j < 4; ++j)
                    fr.acc[i][j] = __builtin_amdgcn_mfma_f32_16x16x32_bf16(
                        af[i], bf[j], fr.acc[i][j], 0, 0, 0);
        }
    }
}

// C/D layout (16x16): col = lane&15, row = (lane>>4)*4 + reg   [m89/m91-verified]

// ---------- QK GEMM: Xb[8192,1024] * Wb[0..2047,1024]^T -> QK[8192,2048] bf16 ----
__global__ __launch_bounds__(256) void gemm_qk(
    const u16* __restrict__ Xb, const u16* __restrict__ Wb, u16* __restrict__ QK)
{
    __shared__ u16 sA[128 * 64];
    __shared__ u16 sB[128 * 64];
    const int row0 = blockIdx.y * 128;
    const int col0 = blockIdx.x * 128;
    Frag128 fr;
    gemm_core_128(Xb, Wb, 1024, 1024, 1024, row0, col0, sA, sB, fr);
    const int cr = (fr.lane >> 4) * 4, cc = fr.lane & 15;
#pragma unroll
    for (int i = 0; i < 4; ++i)
#pragma unroll
        for (int j = 0; j < 4; ++j)
#pragma unroll
            for (int r = 0; r < 4; ++r) {
                int grow = row0 + fr.wm + i * 16 + cr + r;
                int gcol = col0 + fr.wn + j * 16 + cc;
                QK[(long long)grow * 2048 + gcol] = f32_to_bf16(fr.acc[i][j][r]);
            }
}

// ---------- S GEMM: S[b] = Q[b] * K[b]^T (bf16 out, z-batched) ----------
__global__ __launch_bounds__(256) void gemm_s(
    const u16* __restrict__ QK, u16* __restrict__ S)
{
    __shared__ u16 sA[128 * 64];
    __shared__ u16 sB[128 * 64];
    const long long boff = (long long)blockIdx.z * 2048 * 2048;
    const u16* Q  = QK + boff;
    const u16* Kp = QK + boff + 1024;
    u16* Sb = S + boff;
    const int row0 = blockIdx.y * 128;
    const int col0 = blockIdx.x * 128;
    Frag128 fr;
    gemm_core_128(Q, Kp, 1024, 2048, 2048, row0, col0, sA, sB, fr);
    const int cr = (fr.lane >> 4) * 4, cc = fr.lane & 15;
#pragma unroll
    for (int i = 0; i < 4; ++i)
#pragma unroll
        for (int j = 0; j < 4; ++j)
#pragma unroll
            for (int r = 0; r < 4; ++r) {
                int grow = row0 + fr.wm + i * 16 + cr + r;
                int gcol = col0 + fr.wn + j * 16 + cc;
                Sb[(long long)grow * 2048 + gcol] = f32_to_bf16(fr.acc[i][j][r]);
            }
}

// ---------- V GEMM: Xb * Wb[2048..3071]^T, stored transposed -> VT[b][d][s] ----
__global__ __launch_bounds__(256) void gemm_v(
    const u16* __restrict__ Xb, const u16* __restrict__ Wv, u16* __restrict__ VT)
{
    __shared__ u16 sA[128 * 64];
    __shared__ u16 sB[64 * 64];
    const int row0 = blockIdx.y * 128;
    const int col0 = blockIdx.x * 64;
    FragN64 fr;
    gemm_core_n64(Xb, Wv, 1024, 1024, 1024, row0, col0, sA, sB, fr);
    const int cr = (fr.lane >> 4) * 4, cc = fr.lane & 15;
#pragma unroll
    for (int i = 0; i < 2; ++i) {
        int grow = row0 + fr.wm + i * 16 + cr;   // s base, 4-aligned
        int b = grow >> 11, s = grow & 2047;
#pragma unroll
        for (int j = 0; j < 4; ++j) {
            int d = col0 + j * 16 + cc;
            ushort4 o;
            o.x = f32_to_bf16(fr.acc[i][j][0]);
            o.y = f32_to_bf16(fr.acc[i][j][1]);
            o.z = f32_to_bf16(fr.acc[i][j][2]);
            o.w = f32_to_bf16(fr.acc[i][j][3]);
            *(ushort4*)(&VT[((long long)(b * 1024 + d)) * 2048 + s]) = o;
        }
    }
}

// ---------- PV GEMM, transposed formulation: Y^T[b] = VT[b] * P[b]^T ----------
// A = VT_b [1024 d, 2048 k], Bt = P_b [2048 q, 2048 k] -> C[d][q]; stored into
// Y[q][d] so each lane's 4 consecutive C-rows (d) become one float4 store.
// Uses the 128^2 core (MFMA:ds_read 16:8 vs n64's 8:6 — R8 theory for n64's
// 600 TF vs 805).
__global__ __launch_bounds__(256) void gemm_pv_t(
    const u16* __restrict__ P, const u16* __restrict__ VT, float* __restrict__ Y)
{
    __shared__ u16 sA[128 * 64];
    __shared__ u16 sB[128 * 64];
    const u16* VTb = VT + (long long)blockIdx.z * 1024 * 2048;
    const u16* Pb  = P  + (long long)blockIdx.z * 2048 * 2048;
    float* Yb = Y + (long long)blockIdx.z * 2048 * 1024;
    const int row0 = blockIdx.y * 128;   // d
    const int col0 = blockIdx.x * 128;   // q
    Frag128 fr;
    gemm_core_128(VTb, Pb, 2048, 2048, 2048, row0, col0, sA, sB, fr);
    const int cr = (fr.lane >> 4) * 4, cc = fr.lane & 15;
#pragma unroll
    for (int i = 0; i < 4; ++i)
#pragma unroll
        for (int j = 0; j < 4; ++j) {
            int d = row0 + fr.wm + i * 16 + cr;          // 4-aligned
            int q = col0 + fr.wn + j * 16 + cc;
            float4 o = {fr.acc[i][j][0], fr.acc[i][j][1],
                        fr.acc[i][j][2], fr.acc[i][j][3]};
            *(float4*)(&Yb[(long long)q * 1024 + d]) = o;
        }
}

// ---------- softmax over rows of S (bf16, len 2048) -> P (bf16) ----------
__global__ __launch_bounds__(256) void softmax_rows(
    const u16* __restrict__ S, u16* __restrict__ P, float scale)
{
    const long long row = blockIdx.x;
    const u16* s = S + row * 2048;
    u16* p = P + row * 2048;
    const int t = threadIdx.x;
    const int lane = t & 63, w = t >> 6;
    short8 raw = *(const short8*)(s + t * 8);
    float v[8];
    float m = -1e30f;
#pragma unroll
    for (int i = 0; i < 8; ++i) {
        v[i] = bf16_to_f32((u16)raw[i]) * scale;
        m = fmaxf(m, v[i]);
    }
#pragma unroll
    for (int off = 32; off > 0; off >>= 1) m = fmaxf(m, __shfl_xor(m, off, 64));
    __shared__ float sm[4], ss[4];
    if (lane == 0) sm[w] = m;
    __syncthreads();
    m = fmaxf(fmaxf(sm[0], sm[1]), fmaxf(sm[2], sm[3]));
    float sum = 0.f;
#pragma unroll
    for (int i = 0; i < 8; ++i) {
        v[i] = __expf(v[i] - m);
        sum += v[i];
    }
#pragma unroll
    for (int off = 32; off > 0; off >>= 1) sum += __shfl_xor(sum, off, 64);
    if (lane == 0) ss[w] = sum;
    __syncthreads();
    const float inv = 1.0f / (ss[0] + ss[1] + ss[2] + ss[3]);
    short8 o;
#pragma unroll
    for (int i = 0; i < 8; ++i) o[i] = (short)f32_to_bf16(v[i] * inv);
    *(short8*)(p + t * 8) = o;
}

// ---------- launch ----------
extern "C" void kernel_launch(void* const* d_in, const int* in_sizes, int n_in,
                              void* d_out, int out_size, void* d_ws, size_t ws_size,
                              hipStream_t stream) {
    const float* x = (const float*)d_in[0];   // [4,2048,1024]
    const float* W = (const float*)d_in[1];   // [3072,1024]
    float* out = (float*)d_out;               // [4,2048,1024]

    char* ws = (char*)d_ws;
    // layout (bytes): Xb 16.8M | Wb 6.3M | QK 33.6M | VT 16.8M | P 33.6M | S 33.6M
    u16* Xb = (u16*)(ws);
    u16* Wb = (u16*)(ws + 16777216LL);
    u16* QK = (u16*)(ws + 23068672LL);
    u16* VT = (u16*)(ws + 56623104LL);
    u16* P  = (u16*)(ws + 73400320LL);
    u16* S  = (u16*)(ws + 106954752LL);

    // Dependency-adjacent ordering: each consumer launches right after its
    // producer so the producer's output is L2-warm.
    cast_inputs<<<11264, 256, 0, stream>>>(x, Xb, W, Wb,
                                           8192 * 1024 / 4, 3072 * 1024 / 4);
    gemm_qk<<<dim3(16, 64, 1), 256, 0, stream>>>(Xb, Wb, QK);
    gemm_s<<<dim3(16, 16, 4), 256, 0, stream>>>(QK, S);
    softmax_rows<<<8192, 256, 0, stream>>>(S, P, 0.03125f);
    gemm_v<<<dim3(16, 64, 1), 256, 0, stream>>>(Xb, Wb + 2048 * 1024, VT);
    gemm_pv_t<<<dim3(16, 8, 4), 256, 0, stream>>>(P, VT, out);
}